// Round 4
// baseline (500.200 us; speedup 1.0000x reference)
//
#include <hip/hip_runtime.h>
#include <cstdint>
#include <cstddef>

#define BB 32
#define SS 4096
#define DD 512
#define AA 3
#define KK 4
#define OUTD 512

#define NCHUNK 64
#define ROWS_PER_BLOCK (SS / NCHUNK)        // 64
#define ROWS_PER_WAVE  (ROWS_PER_BLOCK / 4) // 16

// Small-weights LDS layout (sw):
// [0..11]  centers (K*A = 12)
// [12..14] ba (3)
// [15..32] Wh (3*6 = 18)   Wh[a][i] at 15 + a*6 + i
// [33..38] bh (6)
// [39..62] Wk (6*4 = 24)   Wk[i][k] at 39 + i*4 + k
// [63..66] bk (4)
//
// R1 lesson: wa[24] permanently live -> allocator pinned 64 VGPR and spilled
//   (768 MiB scratch re-reads). Attributes did not move the allocator.
// R3 lesson: phase-split fixed spills but reads x twice (536 MB of loads).
// R4 design: single x pass; wa re-read from LDS (SoA) per row with
//   #pragma unroll 1 on the a-loop so only 8 wa regs are transiently live.
//   Peak live ~58 regs -> honest 64-VGPR fit. LDS shrunk to ~14.5 KB
//   (shared red[2048] via ds_add_f32) so 8 blocks/CU; grid 2048 blocks.
__global__ __launch_bounds__(256) void fused_pool_kernel(
    const float* __restrict__ x, const float* __restrict__ centers,
    const float* __restrict__ Wa, const float* __restrict__ ba,
    const float* __restrict__ Wh, const float* __restrict__ bh,
    const float* __restrict__ Wk, const float* __restrict__ bk,
    float* __restrict__ pooled)
{
    __shared__ float sw[68];
    __shared__ float wa_lds[AA * DD];     // 6 KB, SoA: wa_lds[a*512 + d]
    __shared__ float red[KK * DD];        // 8 KB, block-shared pooled partial

    const int tid  = threadIdx.x;
    const int wave = tid >> 6;
    const int lane = tid & 63;
    const int b     = blockIdx.y;
    const int chunk = blockIdx.x;

    if (tid < 12)      sw[tid] = centers[tid];
    else if (tid < 15) sw[tid] = ba[tid - 12];
    else if (tid < 33) sw[tid] = Wh[tid - 15];
    else if (tid < 39) sw[tid] = bh[tid - 33];
    else if (tid < 63) sw[tid] = Wk[tid - 39];
    else if (tid < 67) sw[tid] = bk[tid - 63];
    // Wa is [d][a] row-major; stage as SoA [a][d] for per-lane float4 reads
    for (int i = tid; i < AA * DD; i += 256) {
        int d = i / 3, a = i - 3 * d;
        wa_lds[a * DD + d] = Wa[i];
    }
    for (int i = tid; i < KK * DD; i += 256) red[i] = 0.0f;
    __syncthreads();

    const int d0 = lane * 8;
    const int s_base = chunk * ROWS_PER_BLOCK + wave * ROWS_PER_WAVE;
    const float* xb = x + (size_t)b * SS * DD + d0;

    float acc[KK][8];
    #pragma unroll
    for (int k = 0; k < KK; ++k)
        #pragma unroll
        for (int j = 0; j < 8; ++j) acc[k][j] = 0.0f;

    #pragma unroll 1
    for (int i = 0; i < ROWS_PER_WAVE; ++i) {
        const float* xr = xb + (size_t)(s_base + i) * DD;
        float4 x0 = ((const float4*)xr)[0];
        float4 x1 = ((const float4*)xr)[1];
        float xa[8] = {x0.x, x0.y, x0.z, x0.w, x1.x, x1.y, x1.z, x1.w};

        // partial af: wa chunk read from LDS per a; unroll 1 keeps only
        // 8 wa floats live at a time (the R1 spill killer).
        float p[AA];
        #pragma unroll 1
        for (int a = 0; a < AA; ++a) {
            float4 wlo = *(const float4*)(wa_lds + a * DD + d0);
            float4 whi = *(const float4*)(wa_lds + a * DD + d0 + 4);
            p[a] = xa[0] * wlo.x + xa[1] * wlo.y + xa[2] * wlo.z + xa[3] * wlo.w
                 + xa[4] * whi.x + xa[5] * whi.y + xa[6] * whi.z + xa[7] * whi.w;
        }
        // 64-lane butterfly reduce; all lanes get the full af
        #pragma unroll
        for (int off = 32; off >= 1; off >>= 1) {
            p[0] += __shfl_xor(p[0], off, 64);
            p[1] += __shfl_xor(p[1], off, 64);
            p[2] += __shfl_xor(p[2], off, 64);
        }
        const float af0 = p[0] + sw[12];
        const float af1 = p[1] + sw[13];
        const float af2 = p[2] + sw[14];

        float dist[KK];
        #pragma unroll
        for (int k = 0; k < KK; ++k) {
            float da = af0 - sw[k * 3 + 0];
            float db = af1 - sw[k * 3 + 1];
            float dc = af2 - sw[k * 3 + 2];
            dist[k] = sqrtf(da * da + db * db + dc * dc);
        }
        float mn = fminf(fminf(dist[0], dist[1]), fminf(dist[2], dist[3]));
        float e[KK]; float esum = 0.f;
        #pragma unroll
        for (int k = 0; k < KK; ++k) { e[k] = __expf(mn - dist[k]); esum += e[k]; }
        const float einv = 1.0f / esum;

        float h[6];
        #pragma unroll
        for (int i6 = 0; i6 < 6; ++i6) {
            float v = af0 * sw[15 + i6] + af1 * sw[21 + i6]
                    + af2 * sw[27 + i6] + sw[33 + i6];
            h[i6] = fmaxf(v, 0.0f);
        }
        float logit[KK];
        #pragma unroll
        for (int k = 0; k < KK; ++k) {
            float v = sw[63 + k];
            #pragma unroll
            for (int i6 = 0; i6 < 6; ++i6) v += h[i6] * sw[39 + i6 * 4 + k];
            logit[k] = v + e[k] * einv;
        }
        float mx = fmaxf(fmaxf(logit[0], logit[1]), fmaxf(logit[2], logit[3]));
        float f0 = __expf(logit[0] - mx), f1 = __expf(logit[1] - mx);
        float f2 = __expf(logit[2] - mx), f3 = __expf(logit[3] - mx);
        const float finv = 1.0f / (f0 + f1 + f2 + f3);
        f0 *= finv; f1 *= finv; f2 *= finv; f3 *= finv;

        #pragma unroll
        for (int j = 0; j < 8; ++j) {
            acc[0][j] += f0 * xa[j];
            acc[1][j] += f1 * xa[j];
            acc[2][j] += f2 * xa[j];
            acc[3][j] += f3 * xa[j];
        }
    }

    // cross-wave combine via LDS float atomics (ds_add_f32), once per block
    #pragma unroll
    for (int k = 0; k < KK; ++k)
        #pragma unroll
        for (int j = 0; j < 8; ++j)
            atomicAdd(&red[k * DD + d0 + j], acc[k][j]);
    __syncthreads();

    float* pb = pooled + (size_t)b * (KK * DD);
    for (int c = tid; c < KK * DD; c += 256)
        unsafeAtomicAdd(&pb[c], red[c]);
}

// out[b][col] = bout[col] + sum_j pooled[b][j] * Wout[j][col]
// R4: b moved INSIDE (acc[32]/thread) so Wout streams once total (4 MB),
// not once per b. grid (cc 2, jc 16) = 32 blocks; jc partitions j, combined
// via global atomics on out.
__global__ __launch_bounds__(256) void out_gemm_kernel(
    const float* __restrict__ pooled, const float* __restrict__ Wout,
    const float* __restrict__ bout, float* __restrict__ out)
{
    __shared__ float p_sh[BB * 128];   // 16 KB: pooled[b][jc*128 + jj]
    const int tid = threadIdx.x;
    const int cc = blockIdx.x, jc = blockIdx.y;

    for (int idx = tid; idx < BB * 128; idx += 256) {
        int bb = idx >> 7, jj = idx & 127;
        p_sh[idx] = pooled[bb * 2048 + jc * 128 + jj];
    }
    __syncthreads();

    const int col = cc * 256 + tid;
    const float* wp = Wout + (size_t)(jc * 128) * OUTD + col;

    float acc[BB];
    #pragma unroll
    for (int bb = 0; bb < BB; ++bb) acc[bb] = 0.0f;

    #pragma unroll 4
    for (int jj = 0; jj < 128; ++jj) {
        float w = wp[(size_t)jj * OUTD];
        #pragma unroll
        for (int bb = 0; bb < BB; ++bb)
            acc[bb] += p_sh[bb * 128 + jj] * w;   // LDS broadcast read
    }

    const float bo = (jc == 0) ? bout[col] : 0.0f;
    #pragma unroll
    for (int bb = 0; bb < BB; ++bb)
        unsafeAtomicAdd(&out[bb * OUTD + col], acc[bb] + bo);
}

extern "C" void kernel_launch(void* const* d_in, const int* in_sizes, int n_in,
                              void* d_out, int out_size, void* d_ws, size_t ws_size,
                              hipStream_t stream) {
    (void)in_sizes; (void)n_in; (void)out_size; (void)ws_size;
    const float* x       = (const float*)d_in[0];
    const float* centers = (const float*)d_in[1];
    const float* Wa      = (const float*)d_in[2];
    const float* ba      = (const float*)d_in[3];
    const float* Wh      = (const float*)d_in[4];
    const float* bh      = (const float*)d_in[5];
    const float* Wk      = (const float*)d_in[6];
    const float* bk      = (const float*)d_in[7];
    const float* Wout    = (const float*)d_in[8];
    const float* bout    = (const float*)d_in[9];
    float* out    = (float*)d_out;
    float* pooled = (float*)d_ws;   // B*K*D floats = 256 KB

    hipMemsetAsync(pooled, 0, (size_t)BB * KK * DD * sizeof(float), stream);
    hipMemsetAsync(out, 0, (size_t)BB * OUTD * sizeof(float), stream);

    fused_pool_kernel<<<dim3(NCHUNK, BB), 256, 0, stream>>>(
        x, centers, Wa, ba, Wh, bh, Wk, bk, pooled);
    out_gemm_kernel<<<dim3(2, 16), 256, 0, stream>>>(pooled, Wout, bout, out);
}